// Round 7
// baseline (267.183 us; speedup 1.0000x reference)
//
#include <hip/hip_runtime.h>
#include <math.h>

#define LM 512
#define TLEN 1024
#define TINY_F 1.17549435e-38f

typedef float v2f __attribute__((ext_vector_type(2)));

__device__ __forceinline__ v2f pfma(v2f a, v2f b, v2f c) {
    return __builtin_elementwise_fma(a, b, c);
}
__device__ __forceinline__ v2f vs(float c) { return (v2f){c, c}; }

// ---------------------------------------------------------------------------
// DPP helpers. ctrl: row_shr:N = 0x110|N, wave_shr:1 = 0x138,
// row_bcast:15 = 0x142, row_bcast:31 = 0x143
// ---------------------------------------------------------------------------
template<int Ctrl, int RowMask>
__device__ __forceinline__ float fdpp(float oldv, float src) {
    int r = __builtin_amdgcn_update_dpp(
        __builtin_bit_cast(int, oldv), __builtin_bit_cast(int, src),
        Ctrl, RowMask, 0xF, false);
    return __builtin_bit_cast(float, r);
}

// bound_ctrl:1 variant — invalid source lanes read 0.
template<int Ctrl, int RowMask>
__device__ __forceinline__ float fdppb(float src) {
    int r = __builtin_amdgcn_update_dpp(
        0, __builtin_bit_cast(int, src),
        Ctrl, RowMask, 0xF, true);
    return __builtin_bit_cast(float, r);
}

__device__ __forceinline__ float rdlane63(float v) {
    return __builtin_bit_cast(float,
        __builtin_amdgcn_readlane(__builtin_bit_cast(int, v), 63));
}

// inclusive add-scan across 64 lanes (lane63 = grand total)
__device__ __forceinline__ float wave_sum_to63(float v) {
    v += fdpp<0x111, 0xF>(0.f, v);
    v += fdpp<0x112, 0xF>(0.f, v);
    v += fdpp<0x114, 0xF>(0.f, v);
    v += fdpp<0x118, 0xF>(0.f, v);
    v += fdpp<0x142, 0xA>(0.f, v);
    v += fdpp<0x143, 0xC>(0.f, v);
    return v;
}

// ---------------------------------------------------------------------------
// Round-19: SINGLE FUSED KERNEL. Measured: total-dur minus forward-dispatch
// was ~95 us every round (emrel + setup + 2 extra dispatches + P round-trip)
// — 36% of wall for 0.1% of the work. Each of the 128 blocks now derives the
// HMM parameters itself in a ~3 us prologue (parallel across blocks):
//  - all softmaxes are lane-local (8 states/lane; shifted indices j-1
//    recomputed locally, no cross-lane);
//  - cplog prefix = lane-serial-8 + wave DPP inclusive scan (wave_sum_to63
//    IS the scan; excl boundary via one wave_shr DPP, exact);
//  - EmRel rows: each lane computes exactly the 8x25 values it alone reads
//    (pos layout maps state->owner lane; no cross-lane LDS deps).
// Main loop: r1's verified 160us packed STEP (LDS Em) + r6's verified
// enterF fold. Numerics: per-index op orders replicated; only scan/reduce
// association changes (ulp-level, far below the accepted deferred-norm &
// truncated-carry reassociation).
// ---------------------------------------------------------------------------
__global__ __launch_bounds__(64, 1) void hmm_fused(
    const int* __restrict__ seq,
    const float* __restrict__ em, const float* __restrict__ ins,
    const float* __restrict__ flank, const float* __restrict__ btm,
    const float* __restrict__ m2e, const float* __restrict__ mtm,
    const float* __restrict__ m2i, const float* __restrict__ i2m,
    const float* __restrict__ i2i, const float* __restrict__ mtd,
    const float* __restrict__ dtm, const float* __restrict__ dtd,
    const float* __restrict__ lfl, const float* __restrict__ lfe,
    const float* __restrict__ e2u, const float* __restrict__ e2r,
    const float* __restrict__ e2t,
    float* __restrict__ out)
{
    __shared__ __align__(16) float sEmb[25 * 512];
    __shared__ float sLogEi[32];
    __shared__ __align__(16) int sSeq[TLEN + 4];

    const int lane = threadIdx.x;
    const int b = blockIdx.x;
    const int base = lane * 8;

    // ---- stage seq ----
    {
        const int4* s4 = (const int4*)(seq + b * TLEN);
        int4* d4 = (int4*)sSeq;
#pragma unroll
        for (int k = lane; k < 256; k += 64) d4[k] = s4[k];
        if (lane < 4) sSeq[TLEN + lane] = 0;   // pad: lookahead, no clamp
    }

    // ---- insert softmax (serial order preserved; per-lane) ----
    float insp[25];
    {
        float smI = 0.f;
#pragma unroll
        for (int s = 0; s < 25; ++s) smI += expf(ins[s]);
#pragma unroll
        for (int s = 0; s < 25; ++s) insp[s] = expf(ins[s]) / smI;
        if (lane < 25) sLogEi[lane] = log2f(insp[lane]);
    }

    // ---- scalars (uniform, every lane) ----
    const float flv = expf(lfl[0]), fev = expf(lfe[0]);
    const float fsv = flv + fev;
    const float floop = flv / fsv, fexit = fev / fsv;
    const float eu = expf(e2u[0]), er = expf(e2r[0]), et = expf(e2t[0]);
    const float esv = eu + er + et;
    const float ep0 = eu / esv, ep1 = er / esv;
    const float p0 = 1.0f / (1.0f + expf(-flank[0]));
    const float omp0 = 1.0f - p0;

    // ---- per-lane HMM coefficients (all softmaxes lane-local) ----
    float mtm_[8], dtm_[8], wC_[8], mC_[8], dtmM_[8];
    float i2iA[8], m2iSA[8], invNXA[8], m2eA[8], enterA[8];
    {
        float lw[8], plocal[8], ebv[8], m2epJ[8], mtdpJ1[8], lwn[8];
#pragma unroll
        for (int e = 0; e < 8; ++e) {
            const int j = base + e;
            const int jm1 = (j >= 1) ? j - 1 : 0;
            const int jc  = (j < 511) ? j : 510;
            // 4-way + d-softmax at k = j-1 (coeffs consumed by state j)
            {
                float a = expf(mtm[jm1]), bb = expf(m2i[jm1]);
                float c = expf(m2e[jm1]), d = expf(mtd[jm1 + 1]);
                float s4 = a + bb + c + d;
                mtm_[e] = (j >= 1) ? a / s4 : 0.f;
                wC_[e]  = (j >= 1) ? d / s4 : 0.f;
                float da = expf(dtm[jm1]), db = expf(dtd[jm1]);
                float sd = da + db;
                float dtv = da / sd, mcv = db / sd;
                dtm_[e] = (j >= 1) ? dtv : 0.f;
                mC_[e]  = (j >= 1) ? mcv : 0.f;
                lw[e]   = (j >= 1) ? logf(mcv) : 0.f;
            }
            // 4-way + i/d softmax at k = j (own-index coeffs)
            {
                float a = expf(mtm[jc]), bb = expf(m2i[jc]);
                float c = expf(m2e[jc]), d = expf(mtd[jc + 1]);
                float s4 = a + bb + c + d;
                float m2ip = bb / s4;
                m2epJ[e]  = c / s4;
                mtdpJ1[e] = d / s4;
                float ia = expf(i2m[jc]), ib = expf(i2i[jc]);
                float s2 = ia + ib;
                float i2mp = ia / s2;
                i2iA[e] = (j < 511) ? ib / s2 : 0.f;
                float da = expf(dtm[jc]), db = expf(dtd[jc]);
                float sd = da + db;
                lwn[e] = logf(db / sd);   // log(dtdp[j]); used only j<511
                float i2mN = (j + 1 < 512) ? i2mp : 1.0f;
                m2iSA[e]  = ((j < 511) ? m2ip : 0.f) * i2mN;
                invNXA[e] = 1.0f / i2mN;
            }
            ebv[e] = expf(btm[j]);
            plocal[e] = (e == 0) ? lw[0] : plocal[e - 1] + lw[e];
        }
        // wave scans: cplog prefix + begin-softmax total
        float incl = wave_sum_to63(plocal[7]);
        float excl = fdppb<0x138, 0xF>(incl);   // = cplog[base-1], exact
        float cpT  = rdlane63(incl);            // = cplog[511]
        float ebl = ebv[0] + ebv[1] + ebv[2] + ebv[3]
                  + ebv[4] + ebv[5] + ebv[6] + ebv[7];
        float e512 = expf(mtd[0]);
        float tot = rdlane63(wave_sum_to63(ebl)) + e512;
        float mtdp0 = e512 / tot;
#pragma unroll
        for (int e = 0; e < 8; ++e) {
            const int j = base + e;
            float beginp = ebv[e] / tot;
            float cpjm1 = (e == 0) ? excl : excl + plocal[e - 1];
            enterA[e] = beginp
                + ((j >= 1) ? mtdp0 * expf(cpjm1) * dtm_[e] : 0.f);
            float cpj = excl + plocal[e];
            m2eA[e] = (j < 511)
                ? (m2epJ[e] + mtdpJ1[e] * expf(cpT - (cpj + lwn[e])))
                : 1.0f;
        }
        float Mp = mC_[0];
        dtmM_[0] = dtm_[0];
#pragma unroll
        for (int e = 1; e < 8; ++e) { dtmM_[e] = dtm_[e] * Mp; Mp *= mC_[e]; }
    }

    // ---- EmRel rows: lane computes exactly the values it reads in the loop
    {
#pragma unroll
        for (int e = 0; e < 8; ++e) {
            const int j = base + e;
            const float* row = em + j * 25;
            float r[25], ex[25];
#pragma unroll
            for (int s = 0; s < 25; ++s) r[s] = row[s];
            float mx = r[0];
#pragma unroll
            for (int s = 1; s < 25; ++s) mx = fmaxf(mx, r[s]);
            float sme = 0.f;
#pragma unroll
            for (int s = 0; s < 25; ++s) { ex[s] = expf(r[s] - mx); sme += ex[s]; }
            float inv = 1.0f / sme;
            const int pos = ((e >> 2) << 8) | (lane << 2) | (e & 3);
#pragma unroll
            for (int s = 0; s < 25; ++s)
                sEmb[s * 512 + pos] = (ex[s] * inv) / insp[s];
        }
    }
    __syncthreads();

    // one-time: llE = sum over all 1024 symbols of log2(Ei)
    float llE;
    {
        float le = 0.f;
#pragma unroll
        for (int k = 0; k < 16; ++k) le += sLogEi[sSeq[lane * 16 + k]];
        llE = rdlane63(wave_sum_to63(le));
    }

    // ---- pack coefficients (r1 layout) ----
    v2f enter2[4], enterF2[4], m2iS2[4], i2i2[4], m2e2[4], dtmM2[4], invNX2[4];
#pragma unroll
    for (int p = 0; p < 4; ++p) {
        enter2[p]  = (v2f){enterA[2*p], enterA[2*p+1]};
        enterF2[p] = enter2[p] * vs(fexit);
        m2iS2[p]   = (v2f){m2iSA[2*p], m2iSA[2*p+1]};
        i2i2[p]    = (v2f){i2iA[2*p],  i2iA[2*p+1]};
        m2e2[p]    = (v2f){m2eA[2*p],  m2eA[2*p+1]};
        dtmM2[p]   = (v2f){dtmM_[2*p], dtmM_[2*p+1]};
        invNX2[p]  = (v2f){invNXA[2*p], invNXA[2*p+1]};
    }
    const v2f floop2 = vs(floop);
    const v2f epv2 = (v2f){ep0, ep1};

    // packed state: am2[p] = {am[2p], am[2p+1]}; ci2 = pre-scaled inserts
    v2f am2[4], ci2[4];
#define AM(e) ((e) & 1 ? am2[(e) >> 1].y : am2[(e) >> 1].x)
#define CI(e) ((e) & 1 ? ci2[(e) >> 1].y : ci2[(e) >> 1].x)

    // ---- init at t=0 (rescaled: G0 = p0; RF0 = 0) ----
    v2f EmA2[4], EmB2[4];
    {
        int s0 = sSeq[0];
        const float4* c4 = (const float4*)(sEmb + (s0 << 9) + (lane << 2));
        float4 xx = c4[0], yy = c4[64];
        EmA2[0] = (v2f){xx.x, xx.y}; EmA2[1] = (v2f){xx.z, xx.w};
        EmA2[2] = (v2f){yy.x, yy.y}; EmA2[3] = (v2f){yy.z, yy.w};
    }
#pragma unroll
    for (int p = 0; p < 4; ++p) {
        am2[p] = EmA2[p] * vs(omp0) * enter2[p];
        ci2[p] = (v2f){0.f, 0.f};
    }
    v2f GR = (v2f){p0, 0.f};   // {G = f0 + U, RF}
    float ll2 = llE;

    // prime pipeline: EmA <- E_1, symN <- s[2]
    int symN = sSeq[1];
    {
        const float4* c4 = (const float4*)(sEmb + (symN << 9) + (lane << 2));
        float4 xx = c4[0], yy = c4[64];
        EmA2[0] = (v2f){xx.x, xx.y}; EmA2[1] = (v2f){xx.z, xx.w};
        EmA2[2] = (v2f){yy.x, yy.y}; EmA2[3] = (v2f){yy.z, yy.w};
    }
    symN = sSeq[2];
    int sidx = 3;   // next lookahead symbol index

#define STEP(EmC2, EmN2, DO_NORM)                                              \
  {                                                                            \
    { /* prefetch next EmRel column; advance lookahead symbol */               \
      const float4* c4 = (const float4*)(sEmb + (symN << 9) + (lane << 2));    \
      float4 xx = c4[0], yy = c4[64];                                          \
      EmN2[0] = (v2f){xx.x, xx.y}; EmN2[1] = (v2f){xx.z, xx.w};                \
      EmN2[2] = (v2f){yy.x, yy.y}; EmN2[3] = (v2f){yy.z, yy.w};                \
      symN = sSeq[sidx]; ++sidx;                                               \
    }                                                                          \
    float amL = fdppb<0x138, 0xF>(am2[3].y);                                   \
    float ciL = fdppb<0x138, 0xF>(ci2[3].y);                                   \
    /* serial local affine prefix for the delete chain (old am) */             \
    float Apre[8];                                                             \
    Apre[0] = amL * wC_[0];                                                    \
    _Pragma("unroll")                                                          \
    for (int e = 1; e < 8; ++e)                                                \
      Apre[e] = fmaf(Apre[e - 1], mC_[e], AM(e - 1) * wC_[e]);                 \
    /* truncated carry: ONE DPP (dropped term <= Mpre7 ~ 0.4% of carry) */     \
    float carry = fdppb<0x138, 0xF>(Apre[7]);                                  \
    /* dsum: packed seed + exact 6-stage reduction (over old am) */            \
    v2f dv = am2[0] * m2e2[0];                                                 \
    dv = pfma(am2[1], m2e2[1], dv);                                            \
    dv = pfma(am2[2], m2e2[2], dv);                                            \
    dv = pfma(am2[3], m2e2[3], dv);                                            \
    float dsum = rdlane63(wave_sum_to63(dv.x + dv.y));                         \
    /* flank states: Gold read BEFORE update; packed {G,RF} update */          \
    float Gold = GR.x;                                                         \
    GR = pfma(vs(dsum), epv2, GR * floop2);                                    \
    /* t-seeds from OLD am/ci: insert inflow is ci[e-1] DIRECTLY (no mul) */   \
    v2f tp[4];                                                                 \
    tp[0].x = fmaf(amL, mtm_[0], ciL);                                         \
    tp[0].y = fmaf(AM(0), mtm_[1], CI(0));                                     \
    tp[1].x = fmaf(AM(1), mtm_[2], CI(1));                                     \
    tp[1].y = fmaf(AM(2), mtm_[3], CI(2));                                     \
    tp[2].x = fmaf(AM(3), mtm_[4], CI(3));                                     \
    tp[2].y = fmaf(AM(4), mtm_[5], CI(4));                                     \
    tp[3].x = fmaf(AM(5), mtm_[6], CI(5));                                     \
    tp[3].y = fmaf(AM(6), mtm_[7], CI(6));                                     \
    /* packed pre-scaled insert update (old am2, old ci2) */                   \
    ci2[0] = pfma(am2[0], m2iS2[0], ci2[0] * i2i2[0]);                         \
    ci2[1] = pfma(am2[1], m2iS2[1], ci2[1] * i2i2[1]);                         \
    ci2[2] = pfma(am2[2], m2iS2[2], ci2[2] * i2i2[2]);                         \
    ci2[3] = pfma(am2[3], m2iS2[3], ci2[3] * i2i2[3]);                         \
    /* finish match: Gold*enterF (fexit folded) + dtm*Apre + carry, Em */      \
    v2f Gold2 = vs(Gold), carry2 = vs(carry);                                  \
    tp[0] = pfma(Gold2, enterF2[0], tp[0]);                                    \
    tp[1] = pfma(Gold2, enterF2[1], tp[1]);                                    \
    tp[2] = pfma(Gold2, enterF2[2], tp[2]);                                    \
    tp[3] = pfma(Gold2, enterF2[3], tp[3]);                                    \
    tp[0].y = fmaf(dtm_[1], Apre[0], tp[0].y);                                 \
    tp[1].x = fmaf(dtm_[2], Apre[1], tp[1].x);                                 \
    tp[1].y = fmaf(dtm_[3], Apre[2], tp[1].y);                                 \
    tp[2].x = fmaf(dtm_[4], Apre[3], tp[2].x);                                 \
    tp[2].y = fmaf(dtm_[5], Apre[4], tp[2].y);                                 \
    tp[3].x = fmaf(dtm_[6], Apre[5], tp[3].x);                                 \
    tp[3].y = fmaf(dtm_[7], Apre[6], tp[3].y);                                 \
    tp[0] = pfma(dtmM2[0], carry2, tp[0]);                                     \
    tp[1] = pfma(dtmM2[1], carry2, tp[1]);                                     \
    tp[2] = pfma(dtmM2[2], carry2, tp[2]);                                     \
    tp[3] = pfma(dtmM2[3], carry2, tp[3]);                                     \
    am2[0] = EmC2[0] * tp[0];                                                  \
    am2[1] = EmC2[1] * tp[1];                                                  \
    am2[2] = EmC2[2] * tp[2];                                                  \
    am2[3] = EmC2[3] * tp[3];                                                  \
    /* deferred normalization; true insert mass = ci * (1/i2mNext) */          \
    if (DO_NORM) {                                                             \
      v2f ns = pfma(ci2[0], invNX2[0], am2[0]);                                \
      ns += pfma(ci2[1], invNX2[1], am2[1]);                                   \
      ns += pfma(ci2[2], invNX2[2], am2[2]);                                   \
      ns += pfma(ci2[3], invNX2[3], am2[3]);                                   \
      float sl = ns.x + ns.y + ((lane == 0) ? (GR.x + GR.y) : 0.f);            \
      float s = rdlane63(wave_sum_to63(sl)) + TINY_F;                          \
      ll2 += __log2f(s);                                                       \
      float inv = 1.0f / s;                                                    \
      v2f inv2 = vs(inv);                                                      \
      am2[0] *= inv2; am2[1] *= inv2; am2[2] *= inv2; am2[3] *= inv2;          \
      ci2[0] *= inv2; ci2[1] *= inv2; ci2[2] *= inv2; ci2[3] *= inv2;          \
      GR *= inv2;                                                              \
    }                                                                          \
  }

#define PAIR(NORM2)                                                            \
    STEP(EmA2, EmB2, 0)                                                        \
    STEP(EmB2, EmA2, NORM2)

    // 63 chunks x 16 steps (t = 1..1008); norm every 4th chunk (64 steps)
    for (int c = 0; c < 63; ++c) {
        int nf = ((c & 3) == 3);
        PAIR(0) PAIR(0) PAIR(0) PAIR(0)
        PAIR(0) PAIR(0) PAIR(0) PAIR(nf)
    }
    // tail: t = 1009..1023 (15 steps), norm at the final step
    for (int p = 0; p < 7; ++p) {
        PAIR(0)
    }
    STEP(EmA2, EmB2, 1)
#undef PAIR
#undef STEP
#undef AM
#undef CI

    if (lane == 0) out[b] = ll2 * 0.69314718055994530942f;
}

extern "C" void kernel_launch(void* const* d_in, const int* in_sizes, int n_in,
                              void* d_out, int out_size, void* d_ws, size_t ws_size,
                              hipStream_t stream) {
    const int*   seq   = (const int*)d_in[0];
    const float* em    = (const float*)d_in[1];
    const float* ins   = (const float*)d_in[2];
    const float* flank = (const float*)d_in[3];
    const float* btm   = (const float*)d_in[4];
    const float* m2e   = (const float*)d_in[5];
    const float* mtm   = (const float*)d_in[6];
    const float* m2i   = (const float*)d_in[7];
    const float* i2m   = (const float*)d_in[8];
    const float* i2i   = (const float*)d_in[9];
    const float* mtd   = (const float*)d_in[10];
    const float* dtm   = (const float*)d_in[11];
    const float* dtd   = (const float*)d_in[12];
    const float* lfl   = (const float*)d_in[13];
    const float* lfe   = (const float*)d_in[14];
    const float* e2u   = (const float*)d_in[15];
    const float* e2r   = (const float*)d_in[16];
    const float* e2t   = (const float*)d_in[17];
    float* out = (float*)d_out;
    (void)d_ws; (void)ws_size;

    hipLaunchKernelGGL(hmm_fused, dim3(128), dim3(64), 0, stream,
        seq, em, ins, flank, btm, m2e, mtm, m2i, i2m, i2i, mtd, dtm, dtd,
        lfl, lfe, e2u, e2r, e2t, out);
}

// Round 8
// 264.316 us; speedup vs baseline: 1.0108x; 1.0108x over previous
//
#include <hip/hip_runtime.h>
#include <math.h>

#define LM 512
#define TLEN 1024
#define TINY_F 1.17549435e-38f

// d_ws float layout (total 17920 floats = 71680 B)
#define OFF_ENTER 0
#define OFF_MTM   512
#define OFF_I2M   1024   // stores invNX (1/i2mNext), pre-derived
#define OFF_DTM   1536
#define OFF_WC    2048
#define OFF_MC    2560
#define OFF_M2I   3072   // stores m2iS (m2i * i2mNext), pre-derived
#define OFF_I2I   3584
#define OFF_M2E   4096
#define OFF_INS   4608   // log2(insp[s])
#define OFF_SC    4640
#define OFF_EMB   5120   // EmRel = Em/Ei (rescaled recursion)

typedef float v2f __attribute__((ext_vector_type(2)));

__device__ __forceinline__ v2f pfma(v2f a, v2f b, v2f c) {
    return __builtin_elementwise_fma(a, b, c);
}
__device__ __forceinline__ v2f vs(float c) { return (v2f){c, c}; }

// ---------------------------------------------------------------------------
// DPP helpers. ctrl: row_shr:N = 0x110|N, wave_shr:1 = 0x138,
// row_bcast:15 = 0x142, row_bcast:31 = 0x143
// ---------------------------------------------------------------------------
template<int Ctrl, int RowMask>
__device__ __forceinline__ float fdpp(float oldv, float src) {
    int r = __builtin_amdgcn_update_dpp(
        __builtin_bit_cast(int, oldv), __builtin_bit_cast(int, src),
        Ctrl, RowMask, 0xF, false);
    return __builtin_bit_cast(float, r);
}

// bound_ctrl:1 variant — invalid source lanes read 0.
template<int Ctrl, int RowMask>
__device__ __forceinline__ float fdppb(float src) {
    int r = __builtin_amdgcn_update_dpp(
        0, __builtin_bit_cast(int, src),
        Ctrl, RowMask, 0xF, true);
    return __builtin_bit_cast(float, r);
}

__device__ __forceinline__ float rdlane63(float v) {
    return __builtin_bit_cast(float,
        __builtin_amdgcn_readlane(__builtin_bit_cast(int, v), 63));
}

// inclusive add-scan across 64 lanes (lane63 = grand total)
__device__ __forceinline__ float wave_sum_to63(float v) {
    v += fdpp<0x111, 0xF>(0.f, v);
    v += fdpp<0x112, 0xF>(0.f, v);
    v += fdpp<0x114, 0xF>(0.f, v);
    v += fdpp<0x118, 0xF>(0.f, v);
    v += fdpp<0x142, 0xA>(0.f, v);
    v += fdpp<0x143, 0xC>(0.f, v);
    return v;
}

// ---------------------------------------------------------------------------
// PREP: 8 blocks x 64. Every thread builds one EmRel row (verbatim verified
// emrel math). Block 0 additionally derives ALL transition coefficients with
// the r7-verified 64-lane DPP-scan prologue and writes them to P in
// pre-derived form (m2iS / invNX stored directly).
// ---------------------------------------------------------------------------
__global__ __launch_bounds__(64) void hmm_prep(
    const float* __restrict__ em, const float* __restrict__ ins,
    const float* __restrict__ flank, const float* __restrict__ btm,
    const float* __restrict__ m2e, const float* __restrict__ mtm,
    const float* __restrict__ m2i, const float* __restrict__ i2m,
    const float* __restrict__ i2i, const float* __restrict__ mtd,
    const float* __restrict__ dtm, const float* __restrict__ dtd,
    const float* __restrict__ lfl, const float* __restrict__ lfe,
    const float* __restrict__ e2u, const float* __restrict__ e2r,
    const float* __restrict__ e2t, float* __restrict__ P)
{
    const int lane = threadIdx.x;
    const int j = blockIdx.x * 64 + lane;   // row 0..511

    // ---- EmRel row (verbatim verified order) ----
    {
        float sm = 0.f;
        for (int s = 0; s < 25; ++s) sm += expf(ins[s]);
        const float* row = em + j * 25;
        float mx = row[0];
        for (int s = 1; s < 25; ++s) mx = fmaxf(mx, row[s]);
        float sme = 0.f;
        for (int s = 0; s < 25; ++s) sme += expf(row[s] - mx);
        float inv = 1.0f / sme;
        int lanej = j >> 3, e = j & 7;
        int pos = ((e >> 2) << 8) | (lanej << 2) | (e & 3);
        for (int s = 0; s < 25; ++s) {
            float inspS = expf(ins[s]) / sm;
            P[OFF_EMB + s * 512 + pos] = (expf(row[s] - mx) * inv) / inspS;
        }
    }

    if (blockIdx.x != 0) return;

    // ---- block 0: full coefficient derivation (r7-verified math) ----
    const int base = lane * 8;

    // insert softmax (serial order preserved)
    {
        float smI = 0.f;
        for (int s = 0; s < 25; ++s) smI += expf(ins[s]);
        if (lane < 25) P[OFF_INS + lane] = log2f(expf(ins[lane]) / smI);
    }

    const float flv = expf(lfl[0]), fev = expf(lfe[0]);
    const float fsv = flv + fev;
    const float floop = flv / fsv, fexit = fev / fsv;
    const float eu = expf(e2u[0]), er = expf(e2r[0]), et = expf(e2t[0]);
    const float esv = eu + er + et;
    const float ep0 = eu / esv, ep1 = er / esv;
    const float p0 = 1.0f / (1.0f + expf(-flank[0]));

    if (lane == 0) {
        P[OFF_SC + 0] = floop;
        P[OFF_SC + 1] = fexit;
        P[OFF_SC + 2] = p0;
        P[OFF_SC + 5] = ep0;
        P[OFF_SC + 6] = ep1;
        P[OFF_SC + 9] = 1.0f - p0;
    }

    float mtm_[8], dtm_[8], wC_[8], mC_[8];
    float i2iA[8], m2iSA[8], invNXA[8], m2eA[8], enterA[8];
    {
        float lw[8], plocal[8], ebv[8], m2epJ[8], mtdpJ1[8], lwn[8];
#pragma unroll
        for (int e = 0; e < 8; ++e) {
            const int jj = base + e;
            const int jm1 = (jj >= 1) ? jj - 1 : 0;
            const int jc  = (jj < 511) ? jj : 510;
            // 4-way + d-softmax at k = jj-1 (coeffs consumed by state jj)
            {
                float a = expf(mtm[jm1]), bb = expf(m2i[jm1]);
                float c = expf(m2e[jm1]), d = expf(mtd[jm1 + 1]);
                float s4 = a + bb + c + d;
                mtm_[e] = (jj >= 1) ? a / s4 : 0.f;
                wC_[e]  = (jj >= 1) ? d / s4 : 0.f;
                float da = expf(dtm[jm1]), db = expf(dtd[jm1]);
                float sd = da + db;
                float dtv = da / sd, mcv = db / sd;
                dtm_[e] = (jj >= 1) ? dtv : 0.f;
                mC_[e]  = (jj >= 1) ? mcv : 0.f;
                lw[e]   = (jj >= 1) ? logf(mcv) : 0.f;
            }
            // 4-way + i/d softmax at k = jj (own-index coeffs)
            {
                float a = expf(mtm[jc]), bb = expf(m2i[jc]);
                float c = expf(m2e[jc]), d = expf(mtd[jc + 1]);
                float s4 = a + bb + c + d;
                float m2ip = bb / s4;
                m2epJ[e]  = c / s4;
                mtdpJ1[e] = d / s4;
                float ia = expf(i2m[jc]), ib = expf(i2i[jc]);
                float s2 = ia + ib;
                float i2mp = ia / s2;
                i2iA[e] = (jj < 511) ? ib / s2 : 0.f;
                float da = expf(dtm[jc]), db = expf(dtd[jc]);
                float sd = da + db;
                lwn[e] = logf(db / sd);   // log(dtdp[jj]); used only jj<511
                float i2mN = (jj + 1 < 512) ? i2mp : 1.0f;
                m2iSA[e]  = ((jj < 511) ? m2ip : 0.f) * i2mN;
                invNXA[e] = 1.0f / i2mN;
            }
            ebv[e] = expf(btm[jj]);
            plocal[e] = (e == 0) ? lw[0] : plocal[e - 1] + lw[e];
        }
        float incl = wave_sum_to63(plocal[7]);
        float excl = fdppb<0x138, 0xF>(incl);   // = cplog[base-1], exact
        float cpT  = rdlane63(incl);            // = cplog[511]
        float ebl = ebv[0] + ebv[1] + ebv[2] + ebv[3]
                  + ebv[4] + ebv[5] + ebv[6] + ebv[7];
        float e512 = expf(mtd[0]);
        float tot = rdlane63(wave_sum_to63(ebl)) + e512;
        float mtdp0 = e512 / tot;
#pragma unroll
        for (int e = 0; e < 8; ++e) {
            const int jj = base + e;
            float beginp = ebv[e] / tot;
            float cpjm1 = (e == 0) ? excl : excl + plocal[e - 1];
            enterA[e] = beginp
                + ((jj >= 1) ? mtdp0 * expf(cpjm1) * dtm_[e] : 0.f);
            float cpj = excl + plocal[e];
            m2eA[e] = (jj < 511)
                ? (m2epJ[e] + mtdpJ1[e] * expf(cpT - (cpj + lwn[e])))
                : 1.0f;
        }
    }
#pragma unroll
    for (int e = 0; e < 8; ++e) {
        const int jj = base + e;
        P[OFF_ENTER + jj] = enterA[e];
        P[OFF_MTM + jj]   = mtm_[e];
        P[OFF_DTM + jj]   = dtm_[e];
        P[OFF_WC + jj]    = wC_[e];
        P[OFF_MC + jj]    = mC_[e];
        P[OFF_M2I + jj]   = m2iSA[e];   // pre-derived
        P[OFF_I2M + jj]   = invNXA[e];  // pre-derived
        P[OFF_I2I + jj]   = i2iA[e];
        P[OFF_M2E + jj]   = m2eA[e];
    }
}

// ---------------------------------------------------------------------------
// Forward: one wave per batch element (128 blocks) — r1's verified 160 us
// loop + the r6-verified enterF fold. Coefficients come pre-derived from P.
// ---------------------------------------------------------------------------
__global__ __launch_bounds__(64, 1) void hmm_forward(
    const int* __restrict__ seq, const float* __restrict__ P,
    float* __restrict__ out)
{
    __shared__ __align__(16) float sEmb[25 * 512];
    __shared__ float sLogEi[32];
    __shared__ __align__(16) int sSeq[TLEN + 4];

    const int lane = threadIdx.x;
    const int b = blockIdx.x;
    const int base = lane * 8;

    // ---- stage LDS ----
    {
        const float4* src = (const float4*)(P + OFF_EMB);
        float4* dst = (float4*)sEmb;
#pragma unroll 5
        for (int k = lane; k < 25 * 128; k += 64) dst[k] = src[k];
        if (lane < 32) sLogEi[lane] = P[OFF_INS + (lane < 25 ? lane : 0)];
        const int4* s4 = (const int4*)(seq + b * TLEN);
        int4* d4 = (int4*)sSeq;
#pragma unroll
        for (int k = lane; k < 256; k += 64) d4[k] = s4[k];
        if (lane < 4) sSeq[TLEN + lane] = 0;   // pad: lookahead, no clamp
    }
    __syncthreads();

    // one-time: llE = sum over all 1024 symbols of log2(Ei)
    float llE;
    {
        float le = 0.f;
#pragma unroll
        for (int k = 0; k < 16; ++k) le += sLogEi[sSeq[lane * 16 + k]];
        llE = rdlane63(wave_sum_to63(le));
    }

    // ---- per-lane coefficients: scalar for shifted ops, packed for aligned ----
    float mtm_[8], dtm_[8], wC_[8], mC_[8];
    v2f enter2[4], enterF2[4], m2iS2[4], i2i2[4], m2e2[4], dtmM2[4], invNX2[4];
    {
        float enter_[8], m2iS_[8], i2i_[8], m2e_[8], dtmM_[8], invNX_[8];
#pragma unroll
        for (int e = 0; e < 8; ++e) {
            enter_[e] = P[OFF_ENTER + base + e];
            mtm_[e]   = P[OFF_MTM + base + e];
            dtm_[e]   = P[OFF_DTM + base + e];
            wC_[e]    = P[OFF_WC + base + e];
            mC_[e]    = P[OFF_MC + base + e];
            i2i_[e]   = P[OFF_I2I + base + e];
            m2e_[e]   = P[OFF_M2E + base + e];
            m2iS_[e]  = P[OFF_M2I + base + e];   // pre-derived
            invNX_[e] = P[OFF_I2M + base + e];   // pre-derived
        }
        float Mp = mC_[0];
        dtmM_[0] = dtm_[0];
#pragma unroll
        for (int e = 1; e < 8; ++e) { dtmM_[e] = dtm_[e] * Mp; Mp *= mC_[e]; }
#pragma unroll
        for (int p = 0; p < 4; ++p) {
            enter2[p] = (v2f){enter_[2*p], enter_[2*p+1]};
            m2iS2[p]  = (v2f){m2iS_[2*p],  m2iS_[2*p+1]};
            i2i2[p]   = (v2f){i2i_[2*p],   i2i_[2*p+1]};
            m2e2[p]   = (v2f){m2e_[2*p],   m2e_[2*p+1]};
            dtmM2[p]  = (v2f){dtmM_[2*p],  dtmM_[2*p+1]};
            invNX2[p] = (v2f){invNX_[2*p], invNX_[2*p+1]};
        }
    }
    const float floop = P[OFF_SC + 0], fexit = P[OFF_SC + 1], p0 = P[OFF_SC + 2];
    const float ep0 = P[OFF_SC + 5], ep1 = P[OFF_SC + 6];
    const float omp0 = P[OFF_SC + 9];
    const v2f floop2 = vs(floop);
    const v2f epv2 = (v2f){ep0, ep1};
#pragma unroll
    for (int p = 0; p < 4; ++p) enterF2[p] = enter2[p] * vs(fexit);

    // packed state: am2[p] = {am[2p], am[2p+1]}; ci2 = pre-scaled inserts
    v2f am2[4], ci2[4];
#define AM(e) ((e) & 1 ? am2[(e) >> 1].y : am2[(e) >> 1].x)
#define CI(e) ((e) & 1 ? ci2[(e) >> 1].y : ci2[(e) >> 1].x)

    // ---- init at t=0 (rescaled: G0 = p0; RF0 = 0) ----
    v2f EmA2[4], EmB2[4];
    {
        int s0 = sSeq[0];
        const float4* c4 = (const float4*)(sEmb + (s0 << 9) + (lane << 2));
        float4 xx = c4[0], yy = c4[64];
        EmA2[0] = (v2f){xx.x, xx.y}; EmA2[1] = (v2f){xx.z, xx.w};
        EmA2[2] = (v2f){yy.x, yy.y}; EmA2[3] = (v2f){yy.z, yy.w};
    }
#pragma unroll
    for (int p = 0; p < 4; ++p) {
        am2[p] = EmA2[p] * vs(omp0) * enter2[p];
        ci2[p] = (v2f){0.f, 0.f};
    }
    v2f GR = (v2f){p0, 0.f};   // {G = f0 + U, RF}
    float ll2 = llE;

    // prime pipeline: EmA <- E_1, symN <- s[2]
    int symN = sSeq[1];
    {
        const float4* c4 = (const float4*)(sEmb + (symN << 9) + (lane << 2));
        float4 xx = c4[0], yy = c4[64];
        EmA2[0] = (v2f){xx.x, xx.y}; EmA2[1] = (v2f){xx.z, xx.w};
        EmA2[2] = (v2f){yy.x, yy.y}; EmA2[3] = (v2f){yy.z, yy.w};
    }
    symN = sSeq[2];
    int sidx = 3;   // next lookahead symbol index

#define STEP(EmC2, EmN2, DO_NORM)                                              \
  {                                                                            \
    { /* prefetch next EmRel column; advance lookahead symbol */               \
      const float4* c4 = (const float4*)(sEmb + (symN << 9) + (lane << 2));    \
      float4 xx = c4[0], yy = c4[64];                                          \
      EmN2[0] = (v2f){xx.x, xx.y}; EmN2[1] = (v2f){xx.z, xx.w};                \
      EmN2[2] = (v2f){yy.x, yy.y}; EmN2[3] = (v2f){yy.z, yy.w};                \
      symN = sSeq[sidx]; ++sidx;                                               \
    }                                                                          \
    float amL = fdppb<0x138, 0xF>(am2[3].y);                                   \
    float ciL = fdppb<0x138, 0xF>(ci2[3].y);                                   \
    /* serial local affine prefix for the delete chain (old am) */             \
    float Apre[8];                                                             \
    Apre[0] = amL * wC_[0];                                                    \
    _Pragma("unroll")                                                          \
    for (int e = 1; e < 8; ++e)                                                \
      Apre[e] = fmaf(Apre[e - 1], mC_[e], AM(e - 1) * wC_[e]);                 \
    /* truncated carry: ONE DPP (dropped term <= Mpre7 ~ 0.4% of carry) */     \
    float carry = fdppb<0x138, 0xF>(Apre[7]);                                  \
    /* dsum: packed seed + exact 6-stage reduction (over old am) */            \
    v2f dv = am2[0] * m2e2[0];                                                 \
    dv = pfma(am2[1], m2e2[1], dv);                                            \
    dv = pfma(am2[2], m2e2[2], dv);                                            \
    dv = pfma(am2[3], m2e2[3], dv);                                            \
    float dsum = rdlane63(wave_sum_to63(dv.x + dv.y));                         \
    /* flank states: Gold read BEFORE update; packed {G,RF} update */          \
    float Gold = GR.x;                                                         \
    GR = pfma(vs(dsum), epv2, GR * floop2);                                    \
    /* t-seeds from OLD am/ci: insert inflow is ci[e-1] DIRECTLY (no mul) */   \
    v2f tp[4];                                                                 \
    tp[0].x = fmaf(amL, mtm_[0], ciL);                                         \
    tp[0].y = fmaf(AM(0), mtm_[1], CI(0));                                     \
    tp[1].x = fmaf(AM(1), mtm_[2], CI(1));                                     \
    tp[1].y = fmaf(AM(2), mtm_[3], CI(2));                                     \
    tp[2].x = fmaf(AM(3), mtm_[4], CI(3));                                     \
    tp[2].y = fmaf(AM(4), mtm_[5], CI(4));                                     \
    tp[3].x = fmaf(AM(5), mtm_[6], CI(5));                                     \
    tp[3].y = fmaf(AM(6), mtm_[7], CI(6));                                     \
    /* packed pre-scaled insert update (old am2, old ci2) */                   \
    ci2[0] = pfma(am2[0], m2iS2[0], ci2[0] * i2i2[0]);                         \
    ci2[1] = pfma(am2[1], m2iS2[1], ci2[1] * i2i2[1]);                         \
    ci2[2] = pfma(am2[2], m2iS2[2], ci2[2] * i2i2[2]);                         \
    ci2[3] = pfma(am2[3], m2iS2[3], ci2[3] * i2i2[3]);                         \
    /* finish match: Gold*enterF (fexit folded) + dtm*Apre + carry, Em */      \
    v2f Gold2 = vs(Gold), carry2 = vs(carry);                                  \
    tp[0] = pfma(Gold2, enterF2[0], tp[0]);                                    \
    tp[1] = pfma(Gold2, enterF2[1], tp[1]);                                    \
    tp[2] = pfma(Gold2, enterF2[2], tp[2]);                                    \
    tp[3] = pfma(Gold2, enterF2[3], tp[3]);                                    \
    tp[0].y = fmaf(dtm_[1], Apre[0], tp[0].y);                                 \
    tp[1].x = fmaf(dtm_[2], Apre[1], tp[1].x);                                 \
    tp[1].y = fmaf(dtm_[3], Apre[2], tp[1].y);                                 \
    tp[2].x = fmaf(dtm_[4], Apre[3], tp[2].x);                                 \
    tp[2].y = fmaf(dtm_[5], Apre[4], tp[2].y);                                 \
    tp[3].x = fmaf(dtm_[6], Apre[5], tp[3].x);                                 \
    tp[3].y = fmaf(dtm_[7], Apre[6], tp[3].y);                                 \
    tp[0] = pfma(dtmM2[0], carry2, tp[0]);                                     \
    tp[1] = pfma(dtmM2[1], carry2, tp[1]);                                     \
    tp[2] = pfma(dtmM2[2], carry2, tp[2]);                                     \
    tp[3] = pfma(dtmM2[3], carry2, tp[3]);                                     \
    am2[0] = EmC2[0] * tp[0];                                                  \
    am2[1] = EmC2[1] * tp[1];                                                  \
    am2[2] = EmC2[2] * tp[2];                                                  \
    am2[3] = EmC2[3] * tp[3];                                                  \
    /* deferred normalization; true insert mass = ci * (1/i2mNext) */          \
    if (DO_NORM) {                                                             \
      v2f ns = pfma(ci2[0], invNX2[0], am2[0]);                                \
      ns += pfma(ci2[1], invNX2[1], am2[1]);                                   \
      ns += pfma(ci2[2], invNX2[2], am2[2]);                                   \
      ns += pfma(ci2[3], invNX2[3], am2[3]);                                   \
      float sl = ns.x + ns.y + ((lane == 0) ? (GR.x + GR.y) : 0.f);            \
      float s = rdlane63(wave_sum_to63(sl)) + TINY_F;                          \
      ll2 += __log2f(s);                                                       \
      float inv = 1.0f / s;                                                    \
      v2f inv2 = vs(inv);                                                      \
      am2[0] *= inv2; am2[1] *= inv2; am2[2] *= inv2; am2[3] *= inv2;          \
      ci2[0] *= inv2; ci2[1] *= inv2; ci2[2] *= inv2; ci2[3] *= inv2;          \
      GR *= inv2;                                                              \
    }                                                                          \
  }

#define PAIR(NORM2)                                                            \
    STEP(EmA2, EmB2, 0)                                                        \
    STEP(EmB2, EmA2, NORM2)

    // 63 chunks x 16 steps (t = 1..1008); norm every 4th chunk (64 steps)
    for (int c = 0; c < 63; ++c) {
        int nf = ((c & 3) == 3);
        PAIR(0) PAIR(0) PAIR(0) PAIR(0)
        PAIR(0) PAIR(0) PAIR(0) PAIR(nf)
    }
    // tail: t = 1009..1023 (15 steps), norm at the final step
    for (int p = 0; p < 7; ++p) {
        PAIR(0)
    }
    STEP(EmA2, EmB2, 1)
#undef PAIR
#undef STEP
#undef AM
#undef CI

    if (lane == 0) out[b] = ll2 * 0.69314718055994530942f;
}

extern "C" void kernel_launch(void* const* d_in, const int* in_sizes, int n_in,
                              void* d_out, int out_size, void* d_ws, size_t ws_size,
                              hipStream_t stream) {
    const int*   seq   = (const int*)d_in[0];
    const float* em    = (const float*)d_in[1];
    const float* ins   = (const float*)d_in[2];
    const float* flank = (const float*)d_in[3];
    const float* btm   = (const float*)d_in[4];
    const float* m2e   = (const float*)d_in[5];
    const float* mtm   = (const float*)d_in[6];
    const float* m2i   = (const float*)d_in[7];
    const float* i2m   = (const float*)d_in[8];
    const float* i2i   = (const float*)d_in[9];
    const float* mtd   = (const float*)d_in[10];
    const float* dtm   = (const float*)d_in[11];
    const float* dtd   = (const float*)d_in[12];
    const float* lfl   = (const float*)d_in[13];
    const float* lfe   = (const float*)d_in[14];
    const float* e2u   = (const float*)d_in[15];
    const float* e2r   = (const float*)d_in[16];
    const float* e2t   = (const float*)d_in[17];
    float* P = (float*)d_ws;  // needs 71680 B
    float* out = (float*)d_out;

    hipLaunchKernelGGL(hmm_prep, dim3(8), dim3(64), 0, stream,
        em, ins, flank, btm, m2e, mtm, m2i, i2m, i2i, mtd, dtm, dtd,
        lfl, lfe, e2u, e2r, e2t, P);
    hipLaunchKernelGGL(hmm_forward, dim3(128), dim3(64), 0, stream, seq, P, out);
}

// Round 11
// 252.625 us; speedup vs baseline: 1.0576x; 1.0463x over previous
//
#include <hip/hip_runtime.h>
#include <math.h>

#define LM 512
#define TLEN 1024
#define TINY_F 1.17549435e-38f

// d_ws float layout (total 17920 floats = 71680 B)
#define OFF_ENTER 0
#define OFF_MTM   512
#define OFF_I2M   1024   // stores invNX (1/i2mNext), pre-derived
#define OFF_DTM   1536
#define OFF_WC    2048
#define OFF_MC    2560
#define OFF_M2I   3072   // stores m2iS (m2i * i2mNext), pre-derived
#define OFF_I2I   3584
#define OFF_M2E   4096
#define OFF_INS   4608   // log2(insp[s])
#define OFF_SC    4640
#define OFF_EMB   5120   // EmRel = Em/Ei (rescaled recursion)

typedef float v2f __attribute__((ext_vector_type(2)));

__device__ __forceinline__ v2f pfma(v2f a, v2f b, v2f c) {
    return __builtin_elementwise_fma(a, b, c);
}
__device__ __forceinline__ v2f vs(float c) { return (v2f){c, c}; }

// ---------------------------------------------------------------------------
// DPP helpers. ctrl: row_shr:N = 0x110|N, wave_shr:1 = 0x138,
// row_bcast:15 = 0x142, row_bcast:31 = 0x143
// ---------------------------------------------------------------------------
template<int Ctrl, int RowMask>
__device__ __forceinline__ float fdpp(float oldv, float src) {
    int r = __builtin_amdgcn_update_dpp(
        __builtin_bit_cast(int, oldv), __builtin_bit_cast(int, src),
        Ctrl, RowMask, 0xF, false);
    return __builtin_bit_cast(float, r);
}

// bound_ctrl:1 variant — invalid source lanes read 0.
template<int Ctrl, int RowMask>
__device__ __forceinline__ float fdppb(float src) {
    int r = __builtin_amdgcn_update_dpp(
        0, __builtin_bit_cast(int, src),
        Ctrl, RowMask, 0xF, true);
    return __builtin_bit_cast(float, r);
}

__device__ __forceinline__ float rdlane63(float v) {
    return __builtin_bit_cast(float,
        __builtin_amdgcn_readlane(__builtin_bit_cast(int, v), 63));
}

// inclusive add-scan across 64 lanes (lane63 = grand total)
__device__ __forceinline__ float wave_sum_to63(float v) {
    v += fdpp<0x111, 0xF>(0.f, v);
    v += fdpp<0x112, 0xF>(0.f, v);
    v += fdpp<0x114, 0xF>(0.f, v);
    v += fdpp<0x118, 0xF>(0.f, v);
    v += fdpp<0x142, 0xA>(0.f, v);
    v += fdpp<0x143, 0xC>(0.f, v);
    return v;
}

// ---------------------------------------------------------------------------
// PREP: 8 blocks x 64 (unchanged from r8 — verified). Every thread builds one
// EmRel row; block 0 derives all transition coefficients (64-lane DPP scan)
// and writes them pre-derived (m2iS / invNX stored directly).
// ---------------------------------------------------------------------------
__global__ __launch_bounds__(64) void hmm_prep(
    const float* __restrict__ em, const float* __restrict__ ins,
    const float* __restrict__ flank, const float* __restrict__ btm,
    const float* __restrict__ m2e, const float* __restrict__ mtm,
    const float* __restrict__ m2i, const float* __restrict__ i2m,
    const float* __restrict__ i2i, const float* __restrict__ mtd,
    const float* __restrict__ dtm, const float* __restrict__ dtd,
    const float* __restrict__ lfl, const float* __restrict__ lfe,
    const float* __restrict__ e2u, const float* __restrict__ e2r,
    const float* __restrict__ e2t, float* __restrict__ P)
{
    const int lane = threadIdx.x;
    const int j = blockIdx.x * 64 + lane;   // row 0..511

    // ---- EmRel row (verbatim verified order) ----
    {
        float sm = 0.f;
        for (int s = 0; s < 25; ++s) sm += expf(ins[s]);
        const float* row = em + j * 25;
        float mx = row[0];
        for (int s = 1; s < 25; ++s) mx = fmaxf(mx, row[s]);
        float sme = 0.f;
        for (int s = 0; s < 25; ++s) sme += expf(row[s] - mx);
        float inv = 1.0f / sme;
        int lanej = j >> 3, e = j & 7;
        int pos = ((e >> 2) << 8) | (lanej << 2) | (e & 3);
        for (int s = 0; s < 25; ++s) {
            float inspS = expf(ins[s]) / sm;
            P[OFF_EMB + s * 512 + pos] = (expf(row[s] - mx) * inv) / inspS;
        }
    }

    if (blockIdx.x != 0) return;

    // ---- block 0: full coefficient derivation (r7-verified math) ----
    const int base = lane * 8;

    {
        float smI = 0.f;
        for (int s = 0; s < 25; ++s) smI += expf(ins[s]);
        if (lane < 25) P[OFF_INS + lane] = log2f(expf(ins[lane]) / smI);
    }

    const float flv = expf(lfl[0]), fev = expf(lfe[0]);
    const float fsv = flv + fev;
    const float floop = flv / fsv, fexit = fev / fsv;
    const float eu = expf(e2u[0]), er = expf(e2r[0]), et = expf(e2t[0]);
    const float esv = eu + er + et;
    const float ep0 = eu / esv, ep1 = er / esv;
    const float p0 = 1.0f / (1.0f + expf(-flank[0]));

    if (lane == 0) {
        P[OFF_SC + 0] = floop;
        P[OFF_SC + 1] = fexit;
        P[OFF_SC + 2] = p0;
        P[OFF_SC + 5] = ep0;
        P[OFF_SC + 6] = ep1;
        P[OFF_SC + 9] = 1.0f - p0;
    }

    float mtm_[8], dtm_[8], wC_[8], mC_[8];
    float i2iA[8], m2iSA[8], invNXA[8], m2eA[8], enterA[8];
    {
        float lw[8], plocal[8], ebv[8], m2epJ[8], mtdpJ1[8], lwn[8];
#pragma unroll
        for (int e = 0; e < 8; ++e) {
            const int jj = base + e;
            const int jm1 = (jj >= 1) ? jj - 1 : 0;
            const int jc  = (jj < 511) ? jj : 510;
            {
                float a = expf(mtm[jm1]), bb = expf(m2i[jm1]);
                float c = expf(m2e[jm1]), d = expf(mtd[jm1 + 1]);
                float s4 = a + bb + c + d;
                mtm_[e] = (jj >= 1) ? a / s4 : 0.f;
                wC_[e]  = (jj >= 1) ? d / s4 : 0.f;
                float da = expf(dtm[jm1]), db = expf(dtd[jm1]);
                float sd = da + db;
                float dtv = da / sd, mcv = db / sd;
                dtm_[e] = (jj >= 1) ? dtv : 0.f;
                mC_[e]  = (jj >= 1) ? mcv : 0.f;
                lw[e]   = (jj >= 1) ? logf(mcv) : 0.f;
            }
            {
                float a = expf(mtm[jc]), bb = expf(m2i[jc]);
                float c = expf(m2e[jc]), d = expf(mtd[jc + 1]);
                float s4 = a + bb + c + d;
                float m2ip = bb / s4;
                m2epJ[e]  = c / s4;
                mtdpJ1[e] = d / s4;
                float ia = expf(i2m[jc]), ib = expf(i2i[jc]);
                float s2 = ia + ib;
                float i2mp = ia / s2;
                i2iA[e] = (jj < 511) ? ib / s2 : 0.f;
                float da = expf(dtm[jc]), db = expf(dtd[jc]);
                float sd = da + db;
                lwn[e] = logf(db / sd);
                float i2mN = (jj + 1 < 512) ? i2mp : 1.0f;
                m2iSA[e]  = ((jj < 511) ? m2ip : 0.f) * i2mN;
                invNXA[e] = 1.0f / i2mN;
            }
            ebv[e] = expf(btm[jj]);
            plocal[e] = (e == 0) ? lw[0] : plocal[e - 1] + lw[e];
        }
        float incl = wave_sum_to63(plocal[7]);
        float excl = fdppb<0x138, 0xF>(incl);
        float cpT  = rdlane63(incl);
        float ebl = ebv[0] + ebv[1] + ebv[2] + ebv[3]
                  + ebv[4] + ebv[5] + ebv[6] + ebv[7];
        float e512 = expf(mtd[0]);
        float tot = rdlane63(wave_sum_to63(ebl)) + e512;
        float mtdp0 = e512 / tot;
#pragma unroll
        for (int e = 0; e < 8; ++e) {
            const int jj = base + e;
            float beginp = ebv[e] / tot;
            float cpjm1 = (e == 0) ? excl : excl + plocal[e - 1];
            enterA[e] = beginp
                + ((jj >= 1) ? mtdp0 * expf(cpjm1) * dtm_[e] : 0.f);
            float cpj = excl + plocal[e];
            m2eA[e] = (jj < 511)
                ? (m2epJ[e] + mtdpJ1[e] * expf(cpT - (cpj + lwn[e])))
                : 1.0f;
        }
    }
#pragma unroll
    for (int e = 0; e < 8; ++e) {
        const int jj = base + e;
        P[OFF_ENTER + jj] = enterA[e];
        P[OFF_MTM + jj]   = mtm_[e];
        P[OFF_DTM + jj]   = dtm_[e];
        P[OFF_WC + jj]    = wC_[e];
        P[OFF_MC + jj]    = mC_[e];
        P[OFF_M2I + jj]   = m2iSA[e];   // pre-derived
        P[OFF_I2M + jj]   = invNXA[e];  // pre-derived
        P[OFF_I2I + jj]   = i2iA[e];
        P[OFF_M2E + jj]   = m2eA[e];
    }
}

// ---------------------------------------------------------------------------
// Forward: one wave per batch element (128 blocks). r8-verified loop with ONE
// minimal delta (T-pack): the 7 independent am[e-1]*wC[e] products of the
// delete chain pair ALIGNED with am2 against pre-shifted wCsh2 =
// {wC[2p+1], wC[2p+2]} -> 4 pk muls + 7 chain fmas + 1 head mul (was 8 muls
// + 7 fmas). Bitwise-identical products and fma order. The r9/r10 int4
// symbol batching is dropped (two unexplained container failures); symbol
// stream is the proven per-step ds_read.
// ---------------------------------------------------------------------------
__global__ __launch_bounds__(64, 1) void hmm_forward(
    const int* __restrict__ seq, const float* __restrict__ P,
    float* __restrict__ out)
{
    __shared__ __align__(16) float sEmb[25 * 512];
    __shared__ float sLogEi[32];
    __shared__ __align__(16) int sSeq[TLEN + 4];

    const int lane = threadIdx.x;
    const int b = blockIdx.x;
    const int base = lane * 8;

    // ---- stage LDS ----
    {
        const float4* src = (const float4*)(P + OFF_EMB);
        float4* dst = (float4*)sEmb;
#pragma unroll 5
        for (int k = lane; k < 25 * 128; k += 64) dst[k] = src[k];
        if (lane < 32) sLogEi[lane] = P[OFF_INS + (lane < 25 ? lane : 0)];
        const int4* s4 = (const int4*)(seq + b * TLEN);
        int4* d4 = (int4*)sSeq;
#pragma unroll
        for (int k = lane; k < 256; k += 64) d4[k] = s4[k];
        if (lane < 4) sSeq[TLEN + lane] = 0;   // pad: lookahead, no clamp
    }
    __syncthreads();

    // one-time: llE = sum over all 1024 symbols of log2(Ei)
    float llE;
    {
        float le = 0.f;
#pragma unroll
        for (int k = 0; k < 16; ++k) le += sLogEi[sSeq[lane * 16 + k]];
        llE = rdlane63(wave_sum_to63(le));
    }

    // ---- per-lane coefficients: scalar for shifted ops, packed for aligned ----
    float mtm_[8], dtm_[8], wC_[8], mC_[8];
    v2f enter2[4], enterF2[4], m2iS2[4], i2i2[4], m2e2[4], dtmM2[4], invNX2[4];
    v2f wCsh2[4];
    {
        float enter_[8], m2iS_[8], i2i_[8], m2e_[8], dtmM_[8], invNX_[8];
#pragma unroll
        for (int e = 0; e < 8; ++e) {
            enter_[e] = P[OFF_ENTER + base + e];
            mtm_[e]   = P[OFF_MTM + base + e];
            dtm_[e]   = P[OFF_DTM + base + e];
            wC_[e]    = P[OFF_WC + base + e];
            mC_[e]    = P[OFF_MC + base + e];
            i2i_[e]   = P[OFF_I2I + base + e];
            m2e_[e]   = P[OFF_M2E + base + e];
            m2iS_[e]  = P[OFF_M2I + base + e];   // pre-derived
            invNX_[e] = P[OFF_I2M + base + e];   // pre-derived
        }
        float Mp = mC_[0];
        dtmM_[0] = dtm_[0];
#pragma unroll
        for (int e = 1; e < 8; ++e) { dtmM_[e] = dtm_[e] * Mp; Mp *= mC_[e]; }
#pragma unroll
        for (int p = 0; p < 4; ++p) {
            enter2[p] = (v2f){enter_[2*p], enter_[2*p+1]};
            m2iS2[p]  = (v2f){m2iS_[2*p],  m2iS_[2*p+1]};
            i2i2[p]   = (v2f){i2i_[2*p],   i2i_[2*p+1]};
            m2e2[p]   = (v2f){m2e_[2*p],   m2e_[2*p+1]};
            dtmM2[p]  = (v2f){dtmM_[2*p],  dtmM_[2*p+1]};
            invNX2[p] = (v2f){invNX_[2*p], invNX_[2*p+1]};
        }
        wCsh2[0] = (v2f){wC_[1], wC_[2]};
        wCsh2[1] = (v2f){wC_[3], wC_[4]};
        wCsh2[2] = (v2f){wC_[5], wC_[6]};
        wCsh2[3] = (v2f){wC_[7], 0.f};
    }
    const float floop = P[OFF_SC + 0], fexit = P[OFF_SC + 1], p0 = P[OFF_SC + 2];
    const float ep0 = P[OFF_SC + 5], ep1 = P[OFF_SC + 6];
    const float omp0 = P[OFF_SC + 9];
    const v2f floop2 = vs(floop);
    const v2f epv2 = (v2f){ep0, ep1};
#pragma unroll
    for (int p = 0; p < 4; ++p) enterF2[p] = enter2[p] * vs(fexit);

    // packed state: am2[p] = {am[2p], am[2p+1]}; ci2 = pre-scaled inserts
    v2f am2[4], ci2[4];
#define AM(e) ((e) & 1 ? am2[(e) >> 1].y : am2[(e) >> 1].x)
#define CI(e) ((e) & 1 ? ci2[(e) >> 1].y : ci2[(e) >> 1].x)

    // ---- init at t=0 (rescaled: G0 = p0; RF0 = 0) ----
    v2f EmA2[4], EmB2[4];
    {
        int s0 = sSeq[0];
        const float4* c4 = (const float4*)(sEmb + (s0 << 9) + (lane << 2));
        float4 xx = c4[0], yy = c4[64];
        EmA2[0] = (v2f){xx.x, xx.y}; EmA2[1] = (v2f){xx.z, xx.w};
        EmA2[2] = (v2f){yy.x, yy.y}; EmA2[3] = (v2f){yy.z, yy.w};
    }
#pragma unroll
    for (int p = 0; p < 4; ++p) {
        am2[p] = EmA2[p] * vs(omp0) * enter2[p];
        ci2[p] = (v2f){0.f, 0.f};
    }
    v2f GR = (v2f){p0, 0.f};   // {G = f0 + U, RF}
    float ll2 = llE;

    // prime pipeline: EmA <- E_1, symN <- s[2]
    int symN = sSeq[1];
    {
        const float4* c4 = (const float4*)(sEmb + (symN << 9) + (lane << 2));
        float4 xx = c4[0], yy = c4[64];
        EmA2[0] = (v2f){xx.x, xx.y}; EmA2[1] = (v2f){xx.z, xx.w};
        EmA2[2] = (v2f){yy.x, yy.y}; EmA2[3] = (v2f){yy.z, yy.w};
    }
    symN = sSeq[2];
    int sidx = 3;   // next lookahead symbol index

#define STEP(EmC2, EmN2, DO_NORM)                                              \
  {                                                                            \
    { /* prefetch next EmRel column; advance lookahead symbol */               \
      const float4* c4 = (const float4*)(sEmb + (symN << 9) + (lane << 2));    \
      float4 xx = c4[0], yy = c4[64];                                          \
      EmN2[0] = (v2f){xx.x, xx.y}; EmN2[1] = (v2f){xx.z, xx.w};                \
      EmN2[2] = (v2f){yy.x, yy.y}; EmN2[3] = (v2f){yy.z, yy.w};                \
      symN = sSeq[sidx]; ++sidx;                                               \
    }                                                                          \
    float amL = fdppb<0x138, 0xF>(am2[3].y);                                   \
    float ciL = fdppb<0x138, 0xF>(ci2[3].y);                                   \
    /* delete chain: T-pack (aligned pk muls) + serial affine prefix */        \
    v2f T2_0 = am2[0] * wCsh2[0];                                              \
    v2f T2_1 = am2[1] * wCsh2[1];                                              \
    v2f T2_2 = am2[2] * wCsh2[2];                                              \
    v2f T2_3 = am2[3] * wCsh2[3];                                              \
    float Apre[8];                                                             \
    Apre[0] = amL * wC_[0];                                                    \
    Apre[1] = fmaf(Apre[0], mC_[1], T2_0.x);                                   \
    Apre[2] = fmaf(Apre[1], mC_[2], T2_0.y);                                   \
    Apre[3] = fmaf(Apre[2], mC_[3], T2_1.x);                                   \
    Apre[4] = fmaf(Apre[3], mC_[4], T2_1.y);                                   \
    Apre[5] = fmaf(Apre[4], mC_[5], T2_2.x);                                   \
    Apre[6] = fmaf(Apre[5], mC_[6], T2_2.y);                                   \
    Apre[7] = fmaf(Apre[6], mC_[7], T2_3.x);                                   \
    /* truncated carry: ONE DPP (dropped term <= Mpre7 ~ 0.4% of carry) */     \
    float carry = fdppb<0x138, 0xF>(Apre[7]);                                  \
    /* dsum: packed seed + exact 6-stage reduction (over old am) */            \
    v2f dv = am2[0] * m2e2[0];                                                 \
    dv = pfma(am2[1], m2e2[1], dv);                                            \
    dv = pfma(am2[2], m2e2[2], dv);                                            \
    dv = pfma(am2[3], m2e2[3], dv);                                            \
    float dsum = rdlane63(wave_sum_to63(dv.x + dv.y));                         \
    /* flank states: Gold read BEFORE update; packed {G,RF} update */          \
    float Gold = GR.x;                                                         \
    GR = pfma(vs(dsum), epv2, GR * floop2);                                    \
    /* t-seeds from OLD am/ci: insert inflow is ci[e-1] DIRECTLY (no mul) */   \
    v2f tp[4];                                                                 \
    tp[0].x = fmaf(amL, mtm_[0], ciL);                                         \
    tp[0].y = fmaf(AM(0), mtm_[1], CI(0));                                     \
    tp[1].x = fmaf(AM(1), mtm_[2], CI(1));                                     \
    tp[1].y = fmaf(AM(2), mtm_[3], CI(2));                                     \
    tp[2].x = fmaf(AM(3), mtm_[4], CI(3));                                     \
    tp[2].y = fmaf(AM(4), mtm_[5], CI(4));                                     \
    tp[3].x = fmaf(AM(5), mtm_[6], CI(5));                                     \
    tp[3].y = fmaf(AM(6), mtm_[7], CI(6));                                     \
    /* packed pre-scaled insert update (old am2, old ci2) */                   \
    ci2[0] = pfma(am2[0], m2iS2[0], ci2[0] * i2i2[0]);                         \
    ci2[1] = pfma(am2[1], m2iS2[1], ci2[1] * i2i2[1]);                         \
    ci2[2] = pfma(am2[2], m2iS2[2], ci2[2] * i2i2[2]);                         \
    ci2[3] = pfma(am2[3], m2iS2[3], ci2[3] * i2i2[3]);                         \
    /* finish match: Gold*enterF (fexit folded) + dtm*Apre + carry, Em */      \
    v2f Gold2 = vs(Gold), carry2 = vs(carry);                                  \
    tp[0] = pfma(Gold2, enterF2[0], tp[0]);                                    \
    tp[1] = pfma(Gold2, enterF2[1], tp[1]);                                    \
    tp[2] = pfma(Gold2, enterF2[2], tp[2]);                                    \
    tp[3] = pfma(Gold2, enterF2[3], tp[3]);                                    \
    tp[0].y = fmaf(dtm_[1], Apre[0], tp[0].y);                                 \
    tp[1].x = fmaf(dtm_[2], Apre[1], tp[1].x);                                 \
    tp[1].y = fmaf(dtm_[3], Apre[2], tp[1].y);                                 \
    tp[2].x = fmaf(dtm_[4], Apre[3], tp[2].x);                                 \
    tp[2].y = fmaf(dtm_[5], Apre[4], tp[2].y);                                 \
    tp[3].x = fmaf(dtm_[6], Apre[5], tp[3].x);                                 \
    tp[3].y = fmaf(dtm_[7], Apre[6], tp[3].y);                                 \
    tp[0] = pfma(dtmM2[0], carry2, tp[0]);                                     \
    tp[1] = pfma(dtmM2[1], carry2, tp[1]);                                     \
    tp[2] = pfma(dtmM2[2], carry2, tp[2]);                                     \
    tp[3] = pfma(dtmM2[3], carry2, tp[3]);                                     \
    am2[0] = EmC2[0] * tp[0];                                                  \
    am2[1] = EmC2[1] * tp[1];                                                  \
    am2[2] = EmC2[2] * tp[2];                                                  \
    am2[3] = EmC2[3] * tp[3];                                                  \
    /* deferred normalization; true insert mass = ci * (1/i2mNext) */          \
    if (DO_NORM) {                                                             \
      v2f ns = pfma(ci2[0], invNX2[0], am2[0]);                                \
      ns += pfma(ci2[1], invNX2[1], am2[1]);                                   \
      ns += pfma(ci2[2], invNX2[2], am2[2]);                                   \
      ns += pfma(ci2[3], invNX2[3], am2[3]);                                   \
      float sl = ns.x + ns.y + ((lane == 0) ? (GR.x + GR.y) : 0.f);            \
      float s = rdlane63(wave_sum_to63(sl)) + TINY_F;                          \
      ll2 += __log2f(s);                                                       \
      float inv = 1.0f / s;                                                    \
      v2f inv2 = vs(inv);                                                      \
      am2[0] *= inv2; am2[1] *= inv2; am2[2] *= inv2; am2[3] *= inv2;          \
      ci2[0] *= inv2; ci2[1] *= inv2; ci2[2] *= inv2; ci2[3] *= inv2;          \
      GR *= inv2;                                                              \
    }                                                                          \
  }

#define PAIR(NORM2)                                                            \
    STEP(EmA2, EmB2, 0)                                                        \
    STEP(EmB2, EmA2, NORM2)

    // 63 chunks x 16 steps (t = 1..1008); norm every 4th chunk (64 steps)
    for (int c = 0; c < 63; ++c) {
        int nf = ((c & 3) == 3);
        PAIR(0) PAIR(0) PAIR(0) PAIR(0)
        PAIR(0) PAIR(0) PAIR(0) PAIR(nf)
    }
    // tail: t = 1009..1023 (15 steps), norm at the final step
    for (int p = 0; p < 7; ++p) {
        PAIR(0)
    }
    STEP(EmA2, EmB2, 1)
#undef PAIR
#undef STEP
#undef AM
#undef CI

    if (lane == 0) out[b] = ll2 * 0.69314718055994530942f;
}

extern "C" void kernel_launch(void* const* d_in, const int* in_sizes, int n_in,
                              void* d_out, int out_size, void* d_ws, size_t ws_size,
                              hipStream_t stream) {
    const int*   seq   = (const int*)d_in[0];
    const float* em    = (const float*)d_in[1];
    const float* ins   = (const float*)d_in[2];
    const float* flank = (const float*)d_in[3];
    const float* btm   = (const float*)d_in[4];
    const float* m2e   = (const float*)d_in[5];
    const float* mtm   = (const float*)d_in[6];
    const float* m2i   = (const float*)d_in[7];
    const float* i2m   = (const float*)d_in[8];
    const float* i2i   = (const float*)d_in[9];
    const float* mtd   = (const float*)d_in[10];
    const float* dtm   = (const float*)d_in[11];
    const float* dtd   = (const float*)d_in[12];
    const float* lfl   = (const float*)d_in[13];
    const float* lfe   = (const float*)d_in[14];
    const float* e2u   = (const float*)d_in[15];
    const float* e2r   = (const float*)d_in[16];
    const float* e2t   = (const float*)d_in[17];
    float* P = (float*)d_ws;  // needs 71680 B
    float* out = (float*)d_out;

    hipLaunchKernelGGL(hmm_prep, dim3(8), dim3(64), 0, stream,
        em, ins, flank, btm, m2e, mtm, m2i, i2m, i2i, mtd, dtm, dtd,
        lfl, lfe, e2u, e2r, e2t, P);
    hipLaunchKernelGGL(hmm_forward, dim3(128), dim3(64), 0, stream, seq, P, out);
}

// Round 12
// 252.146 us; speedup vs baseline: 1.0596x; 1.0019x over previous
//
#include <hip/hip_runtime.h>
#include <math.h>

#define LM 512
#define TLEN 1024
#define TINY_F 1.17549435e-38f

// d_ws float layout (total 17920 floats = 71680 B)
#define OFF_ENTER 0
#define OFF_MTM   512
#define OFF_I2M   1024   // stores invNX (1/i2mNext), pre-derived
#define OFF_DTM   1536
#define OFF_WC    2048
#define OFF_MC    2560
#define OFF_M2I   3072   // stores m2iS (m2i * i2mNext), pre-derived
#define OFF_I2I   3584
#define OFF_M2E   4096
#define OFF_INS   4608   // log2(insp[s])
#define OFF_SC    4640
#define OFF_EMB   5120   // EmRel = Em/Ei (rescaled recursion)

typedef float v2f __attribute__((ext_vector_type(2)));

__device__ __forceinline__ v2f pfma(v2f a, v2f b, v2f c) {
    return __builtin_elementwise_fma(a, b, c);
}
__device__ __forceinline__ v2f vs(float c) { return (v2f){c, c}; }

// ---------------------------------------------------------------------------
// DPP helpers. ctrl: row_shr:N = 0x110|N, wave_shr:1 = 0x138,
// row_bcast:15 = 0x142, row_bcast:31 = 0x143
// ---------------------------------------------------------------------------
template<int Ctrl, int RowMask>
__device__ __forceinline__ float fdpp(float oldv, float src) {
    int r = __builtin_amdgcn_update_dpp(
        __builtin_bit_cast(int, oldv), __builtin_bit_cast(int, src),
        Ctrl, RowMask, 0xF, false);
    return __builtin_bit_cast(float, r);
}

// bound_ctrl:1 variant — invalid source lanes read 0.
template<int Ctrl, int RowMask>
__device__ __forceinline__ float fdppb(float src) {
    int r = __builtin_amdgcn_update_dpp(
        0, __builtin_bit_cast(int, src),
        Ctrl, RowMask, 0xF, true);
    return __builtin_bit_cast(float, r);
}

__device__ __forceinline__ float rdlane63(float v) {
    return __builtin_bit_cast(float,
        __builtin_amdgcn_readlane(__builtin_bit_cast(int, v), 63));
}

// inclusive add-scan across 64 lanes (lane63 = grand total)
__device__ __forceinline__ float wave_sum_to63(float v) {
    v += fdpp<0x111, 0xF>(0.f, v);
    v += fdpp<0x112, 0xF>(0.f, v);
    v += fdpp<0x114, 0xF>(0.f, v);
    v += fdpp<0x118, 0xF>(0.f, v);
    v += fdpp<0x142, 0xA>(0.f, v);
    v += fdpp<0x143, 0xC>(0.f, v);
    return v;
}

// ---------------------------------------------------------------------------
// PREP: 8 blocks x 64 (unchanged — verified). Every thread builds one EmRel
// row; block 0 derives all transition coefficients (64-lane DPP scan) and
// writes them pre-derived (m2iS / invNX stored directly).
// ---------------------------------------------------------------------------
__global__ __launch_bounds__(64) void hmm_prep(
    const float* __restrict__ em, const float* __restrict__ ins,
    const float* __restrict__ flank, const float* __restrict__ btm,
    const float* __restrict__ m2e, const float* __restrict__ mtm,
    const float* __restrict__ m2i, const float* __restrict__ i2m,
    const float* __restrict__ i2i, const float* __restrict__ mtd,
    const float* __restrict__ dtm, const float* __restrict__ dtd,
    const float* __restrict__ lfl, const float* __restrict__ lfe,
    const float* __restrict__ e2u, const float* __restrict__ e2r,
    const float* __restrict__ e2t, float* __restrict__ P)
{
    const int lane = threadIdx.x;
    const int j = blockIdx.x * 64 + lane;   // row 0..511

    // ---- EmRel row (verbatim verified order) ----
    {
        float sm = 0.f;
        for (int s = 0; s < 25; ++s) sm += expf(ins[s]);
        const float* row = em + j * 25;
        float mx = row[0];
        for (int s = 1; s < 25; ++s) mx = fmaxf(mx, row[s]);
        float sme = 0.f;
        for (int s = 0; s < 25; ++s) sme += expf(row[s] - mx);
        float inv = 1.0f / sme;
        int lanej = j >> 3, e = j & 7;
        int pos = ((e >> 2) << 8) | (lanej << 2) | (e & 3);
        for (int s = 0; s < 25; ++s) {
            float inspS = expf(ins[s]) / sm;
            P[OFF_EMB + s * 512 + pos] = (expf(row[s] - mx) * inv) / inspS;
        }
    }

    if (blockIdx.x != 0) return;

    // ---- block 0: full coefficient derivation (verified math) ----
    const int base = lane * 8;

    {
        float smI = 0.f;
        for (int s = 0; s < 25; ++s) smI += expf(ins[s]);
        if (lane < 25) P[OFF_INS + lane] = log2f(expf(ins[lane]) / smI);
    }

    const float flv = expf(lfl[0]), fev = expf(lfe[0]);
    const float fsv = flv + fev;
    const float floop = flv / fsv, fexit = fev / fsv;
    const float eu = expf(e2u[0]), er = expf(e2r[0]), et = expf(e2t[0]);
    const float esv = eu + er + et;
    const float ep0 = eu / esv, ep1 = er / esv;
    const float p0 = 1.0f / (1.0f + expf(-flank[0]));

    if (lane == 0) {
        P[OFF_SC + 0] = floop;
        P[OFF_SC + 1] = fexit;
        P[OFF_SC + 2] = p0;
        P[OFF_SC + 5] = ep0;
        P[OFF_SC + 6] = ep1;
        P[OFF_SC + 9] = 1.0f - p0;
    }

    float mtm_[8], dtm_[8], wC_[8], mC_[8];
    float i2iA[8], m2iSA[8], invNXA[8], m2eA[8], enterA[8];
    {
        float lw[8], plocal[8], ebv[8], m2epJ[8], mtdpJ1[8], lwn[8];
#pragma unroll
        for (int e = 0; e < 8; ++e) {
            const int jj = base + e;
            const int jm1 = (jj >= 1) ? jj - 1 : 0;
            const int jc  = (jj < 511) ? jj : 510;
            {
                float a = expf(mtm[jm1]), bb = expf(m2i[jm1]);
                float c = expf(m2e[jm1]), d = expf(mtd[jm1 + 1]);
                float s4 = a + bb + c + d;
                mtm_[e] = (jj >= 1) ? a / s4 : 0.f;
                wC_[e]  = (jj >= 1) ? d / s4 : 0.f;
                float da = expf(dtm[jm1]), db = expf(dtd[jm1]);
                float sd = da + db;
                float dtv = da / sd, mcv = db / sd;
                dtm_[e] = (jj >= 1) ? dtv : 0.f;
                mC_[e]  = (jj >= 1) ? mcv : 0.f;
                lw[e]   = (jj >= 1) ? logf(mcv) : 0.f;
            }
            {
                float a = expf(mtm[jc]), bb = expf(m2i[jc]);
                float c = expf(m2e[jc]), d = expf(mtd[jc + 1]);
                float s4 = a + bb + c + d;
                float m2ip = bb / s4;
                m2epJ[e]  = c / s4;
                mtdpJ1[e] = d / s4;
                float ia = expf(i2m[jc]), ib = expf(i2i[jc]);
                float s2 = ia + ib;
                float i2mp = ia / s2;
                i2iA[e] = (jj < 511) ? ib / s2 : 0.f;
                float da = expf(dtm[jc]), db = expf(dtd[jc]);
                float sd = da + db;
                lwn[e] = logf(db / sd);
                float i2mN = (jj + 1 < 512) ? i2mp : 1.0f;
                m2iSA[e]  = ((jj < 511) ? m2ip : 0.f) * i2mN;
                invNXA[e] = 1.0f / i2mN;
            }
            ebv[e] = expf(btm[jj]);
            plocal[e] = (e == 0) ? lw[0] : plocal[e - 1] + lw[e];
        }
        float incl = wave_sum_to63(plocal[7]);
        float excl = fdppb<0x138, 0xF>(incl);
        float cpT  = rdlane63(incl);
        float ebl = ebv[0] + ebv[1] + ebv[2] + ebv[3]
                  + ebv[4] + ebv[5] + ebv[6] + ebv[7];
        float e512 = expf(mtd[0]);
        float tot = rdlane63(wave_sum_to63(ebl)) + e512;
        float mtdp0 = e512 / tot;
#pragma unroll
        for (int e = 0; e < 8; ++e) {
            const int jj = base + e;
            float beginp = ebv[e] / tot;
            float cpjm1 = (e == 0) ? excl : excl + plocal[e - 1];
            enterA[e] = beginp
                + ((jj >= 1) ? mtdp0 * expf(cpjm1) * dtm_[e] : 0.f);
            float cpj = excl + plocal[e];
            m2eA[e] = (jj < 511)
                ? (m2epJ[e] + mtdpJ1[e] * expf(cpT - (cpj + lwn[e])))
                : 1.0f;
        }
    }
#pragma unroll
    for (int e = 0; e < 8; ++e) {
        const int jj = base + e;
        P[OFF_ENTER + jj] = enterA[e];
        P[OFF_MTM + jj]   = mtm_[e];
        P[OFF_DTM + jj]   = dtm_[e];
        P[OFF_WC + jj]    = wC_[e];
        P[OFF_MC + jj]    = mC_[e];
        P[OFF_M2I + jj]   = m2iSA[e];   // pre-derived
        P[OFF_I2M + jj]   = invNXA[e];  // pre-derived
        P[OFF_I2I + jj]   = i2iA[e];
        P[OFF_M2E + jj]   = m2eA[e];
    }
}

// ---------------------------------------------------------------------------
// Forward: one wave per batch element (128 blocks). r11-verified loop
// (T-pack, 153.5 us) + QUAD symbol batching: one ds_read_b128 per 4 steps
// (int4 register, statically phased; r9/r10 container failures were
// infra-correlated — r11's degraded push times — and the phasing audit is
// clean: 256 reloads, final read = sSeq[1024..1027] zero pad, in bounds).
// ---------------------------------------------------------------------------
__global__ __launch_bounds__(64, 1) void hmm_forward(
    const int* __restrict__ seq, const float* __restrict__ P,
    float* __restrict__ out)
{
    __shared__ __align__(16) float sEmb[25 * 512];
    __shared__ float sLogEi[32];
    __shared__ __align__(16) int sSeq[TLEN + 4];

    const int lane = threadIdx.x;
    const int b = blockIdx.x;
    const int base = lane * 8;

    // ---- stage LDS ----
    {
        const float4* src = (const float4*)(P + OFF_EMB);
        float4* dst = (float4*)sEmb;
#pragma unroll 5
        for (int k = lane; k < 25 * 128; k += 64) dst[k] = src[k];
        if (lane < 32) sLogEi[lane] = P[OFF_INS + (lane < 25 ? lane : 0)];
        const int4* s4 = (const int4*)(seq + b * TLEN);
        int4* d4 = (int4*)sSeq;
#pragma unroll
        for (int k = lane; k < 256; k += 64) d4[k] = s4[k];
        if (lane < 4) sSeq[TLEN + lane] = 0;   // pad: final int4 reload lands here
    }
    __syncthreads();

    // one-time: llE = sum over all 1024 symbols of log2(Ei)
    float llE;
    {
        float le = 0.f;
#pragma unroll
        for (int k = 0; k < 16; ++k) le += sLogEi[sSeq[lane * 16 + k]];
        llE = rdlane63(wave_sum_to63(le));
    }

    // ---- per-lane coefficients: scalar for shifted ops, packed for aligned ----
    float mtm_[8], dtm_[8], wC_[8], mC_[8];
    v2f enter2[4], enterF2[4], m2iS2[4], i2i2[4], m2e2[4], dtmM2[4], invNX2[4];
    v2f wCsh2[4];
    {
        float enter_[8], m2iS_[8], i2i_[8], m2e_[8], dtmM_[8], invNX_[8];
#pragma unroll
        for (int e = 0; e < 8; ++e) {
            enter_[e] = P[OFF_ENTER + base + e];
            mtm_[e]   = P[OFF_MTM + base + e];
            dtm_[e]   = P[OFF_DTM + base + e];
            wC_[e]    = P[OFF_WC + base + e];
            mC_[e]    = P[OFF_MC + base + e];
            i2i_[e]   = P[OFF_I2I + base + e];
            m2e_[e]   = P[OFF_M2E + base + e];
            m2iS_[e]  = P[OFF_M2I + base + e];   // pre-derived
            invNX_[e] = P[OFF_I2M + base + e];   // pre-derived
        }
        float Mp = mC_[0];
        dtmM_[0] = dtm_[0];
#pragma unroll
        for (int e = 1; e < 8; ++e) { dtmM_[e] = dtm_[e] * Mp; Mp *= mC_[e]; }
#pragma unroll
        for (int p = 0; p < 4; ++p) {
            enter2[p] = (v2f){enter_[2*p], enter_[2*p+1]};
            m2iS2[p]  = (v2f){m2iS_[2*p],  m2iS_[2*p+1]};
            i2i2[p]   = (v2f){i2i_[2*p],   i2i_[2*p+1]};
            m2e2[p]   = (v2f){m2e_[2*p],   m2e_[2*p+1]};
            dtmM2[p]  = (v2f){dtmM_[2*p],  dtmM_[2*p+1]};
            invNX2[p] = (v2f){invNX_[2*p], invNX_[2*p+1]};
        }
        wCsh2[0] = (v2f){wC_[1], wC_[2]};
        wCsh2[1] = (v2f){wC_[3], wC_[4]};
        wCsh2[2] = (v2f){wC_[5], wC_[6]};
        wCsh2[3] = (v2f){wC_[7], 0.f};
    }
    const float floop = P[OFF_SC + 0], fexit = P[OFF_SC + 1], p0 = P[OFF_SC + 2];
    const float ep0 = P[OFF_SC + 5], ep1 = P[OFF_SC + 6];
    const float omp0 = P[OFF_SC + 9];
    const v2f floop2 = vs(floop);
    const v2f epv2 = (v2f){ep0, ep1};
#pragma unroll
    for (int p = 0; p < 4; ++p) enterF2[p] = enter2[p] * vs(fexit);

    // packed state: am2[p] = {am[2p], am[2p+1]}; ci2 = pre-scaled inserts
    v2f am2[4], ci2[4];
#define AM(e) ((e) & 1 ? am2[(e) >> 1].y : am2[(e) >> 1].x)
#define CI(e) ((e) & 1 ? ci2[(e) >> 1].y : ci2[(e) >> 1].x)

    // ---- symbol stream: int4-batched (block-aligned, statically phased) ----
    int4 sy = *(const int4*)sSeq;        // symbols 0..3
    const int* sp = sSeq + 4;            // next block
    int symN;

    // ---- init at t=0 (rescaled: G0 = p0; RF0 = 0) ----
    v2f EmA2[4], EmB2[4];
    {
        int s0 = sy.x;
        const float4* c4 = (const float4*)(sEmb + (s0 << 9) + (lane << 2));
        float4 xx = c4[0], yy = c4[64];
        EmA2[0] = (v2f){xx.x, xx.y}; EmA2[1] = (v2f){xx.z, xx.w};
        EmA2[2] = (v2f){yy.x, yy.y}; EmA2[3] = (v2f){yy.z, yy.w};
    }
#pragma unroll
    for (int p = 0; p < 4; ++p) {
        am2[p] = EmA2[p] * vs(omp0) * enter2[p];
        ci2[p] = (v2f){0.f, 0.f};
    }
    v2f GR = (v2f){p0, 0.f};   // {G = f0 + U, RF}
    float ll2 = llE;

    // prime pipeline: EmA <- E_1 (symbol sy.y), symN <- sy.z (symbol 2)
    {
        int s1 = sy.y;
        const float4* c4 = (const float4*)(sEmb + (s1 << 9) + (lane << 2));
        float4 xx = c4[0], yy = c4[64];
        EmA2[0] = (v2f){xx.x, xx.y}; EmA2[1] = (v2f){xx.z, xx.w};
        EmA2[2] = (v2f){yy.x, yy.y}; EmA2[3] = (v2f){yy.z, yy.w};
    }
    symN = sy.z;

// STEP: one timestep. SYMX = component of sy for the next lookahead symbol;
// RELOAD=1 -> refill sy (only on the .w phase). symN = SYMX is read BEFORE
// the reload, so the lookahead always comes from the pre-reload sy.
#define STEP(EmC2, EmN2, DO_NORM, SYMX, RELOAD)                                \
  {                                                                            \
    { /* prefetch next EmRel column; advance lookahead symbol */               \
      const float4* c4 = (const float4*)(sEmb + (symN << 9) + (lane << 2));    \
      float4 xx = c4[0], yy = c4[64];                                          \
      EmN2[0] = (v2f){xx.x, xx.y}; EmN2[1] = (v2f){xx.z, xx.w};                \
      EmN2[2] = (v2f){yy.x, yy.y}; EmN2[3] = (v2f){yy.z, yy.w};                \
      symN = SYMX;                                                             \
      if (RELOAD) { sy = *(const int4*)sp; sp += 4; }                          \
    }                                                                          \
    float amL = fdppb<0x138, 0xF>(am2[3].y);                                   \
    float ciL = fdppb<0x138, 0xF>(ci2[3].y);                                   \
    /* delete chain: T-pack (aligned pk muls) + serial affine prefix */        \
    v2f T2_0 = am2[0] * wCsh2[0];                                              \
    v2f T2_1 = am2[1] * wCsh2[1];                                              \
    v2f T2_2 = am2[2] * wCsh2[2];                                              \
    v2f T2_3 = am2[3] * wCsh2[3];                                              \
    float Apre[8];                                                             \
    Apre[0] = amL * wC_[0];                                                    \
    Apre[1] = fmaf(Apre[0], mC_[1], T2_0.x);                                   \
    Apre[2] = fmaf(Apre[1], mC_[2], T2_0.y);                                   \
    Apre[3] = fmaf(Apre[2], mC_[3], T2_1.x);                                   \
    Apre[4] = fmaf(Apre[3], mC_[4], T2_1.y);                                   \
    Apre[5] = fmaf(Apre[4], mC_[5], T2_2.x);                                   \
    Apre[6] = fmaf(Apre[5], mC_[6], T2_2.y);                                   \
    Apre[7] = fmaf(Apre[6], mC_[7], T2_3.x);                                   \
    /* truncated carry: ONE DPP (dropped term <= Mpre7 ~ 0.4% of carry) */     \
    float carry = fdppb<0x138, 0xF>(Apre[7]);                                  \
    /* dsum: packed seed + exact 6-stage reduction (over old am) */            \
    v2f dv = am2[0] * m2e2[0];                                                 \
    dv = pfma(am2[1], m2e2[1], dv);                                            \
    dv = pfma(am2[2], m2e2[2], dv);                                            \
    dv = pfma(am2[3], m2e2[3], dv);                                            \
    float dsum = rdlane63(wave_sum_to63(dv.x + dv.y));                         \
    /* flank states: Gold read BEFORE update; packed {G,RF} update */          \
    float Gold = GR.x;                                                         \
    GR = pfma(vs(dsum), epv2, GR * floop2);                                    \
    /* t-seeds from OLD am/ci: insert inflow is ci[e-1] DIRECTLY (no mul) */   \
    v2f tp[4];                                                                 \
    tp[0].x = fmaf(amL, mtm_[0], ciL);                                         \
    tp[0].y = fmaf(AM(0), mtm_[1], CI(0));                                     \
    tp[1].x = fmaf(AM(1), mtm_[2], CI(1));                                     \
    tp[1].y = fmaf(AM(2), mtm_[3], CI(2));                                     \
    tp[2].x = fmaf(AM(3), mtm_[4], CI(3));                                     \
    tp[2].y = fmaf(AM(4), mtm_[5], CI(4));                                     \
    tp[3].x = fmaf(AM(5), mtm_[6], CI(5));                                     \
    tp[3].y = fmaf(AM(6), mtm_[7], CI(6));                                     \
    /* packed pre-scaled insert update (old am2, old ci2) */                   \
    ci2[0] = pfma(am2[0], m2iS2[0], ci2[0] * i2i2[0]);                         \
    ci2[1] = pfma(am2[1], m2iS2[1], ci2[1] * i2i2[1]);                         \
    ci2[2] = pfma(am2[2], m2iS2[2], ci2[2] * i2i2[2]);                         \
    ci2[3] = pfma(am2[3], m2iS2[3], ci2[3] * i2i2[3]);                         \
    /* finish match: Gold*enterF (fexit folded) + dtm*Apre + carry, Em */      \
    v2f Gold2 = vs(Gold), carry2 = vs(carry);                                  \
    tp[0] = pfma(Gold2, enterF2[0], tp[0]);                                    \
    tp[1] = pfma(Gold2, enterF2[1], tp[1]);                                    \
    tp[2] = pfma(Gold2, enterF2[2], tp[2]);                                    \
    tp[3] = pfma(Gold2, enterF2[3], tp[3]);                                    \
    tp[0].y = fmaf(dtm_[1], Apre[0], tp[0].y);                                 \
    tp[1].x = fmaf(dtm_[2], Apre[1], tp[1].x);                                 \
    tp[1].y = fmaf(dtm_[3], Apre[2], tp[1].y);                                 \
    tp[2].x = fmaf(dtm_[4], Apre[3], tp[2].x);                                 \
    tp[2].y = fmaf(dtm_[5], Apre[4], tp[2].y);                                 \
    tp[3].x = fmaf(dtm_[6], Apre[5], tp[3].x);                                 \
    tp[3].y = fmaf(dtm_[7], Apre[6], tp[3].y);                                 \
    tp[0] = pfma(dtmM2[0], carry2, tp[0]);                                     \
    tp[1] = pfma(dtmM2[1], carry2, tp[1]);                                     \
    tp[2] = pfma(dtmM2[2], carry2, tp[2]);                                     \
    tp[3] = pfma(dtmM2[3], carry2, tp[3]);                                     \
    am2[0] = EmC2[0] * tp[0];                                                  \
    am2[1] = EmC2[1] * tp[1];                                                  \
    am2[2] = EmC2[2] * tp[2];                                                  \
    am2[3] = EmC2[3] * tp[3];                                                  \
    /* deferred normalization; true insert mass = ci * (1/i2mNext) */          \
    if (DO_NORM) {                                                             \
      v2f ns = pfma(ci2[0], invNX2[0], am2[0]);                                \
      ns += pfma(ci2[1], invNX2[1], am2[1]);                                   \
      ns += pfma(ci2[2], invNX2[2], am2[2]);                                   \
      ns += pfma(ci2[3], invNX2[3], am2[3]);                                   \
      float sl = ns.x + ns.y + ((lane == 0) ? (GR.x + GR.y) : 0.f);            \
      float s = rdlane63(wave_sum_to63(sl)) + TINY_F;                          \
      ll2 += __log2f(s);                                                       \
      float inv = 1.0f / s;                                                    \
      v2f inv2 = vs(inv);                                                      \
      am2[0] *= inv2; am2[1] *= inv2; am2[2] *= inv2; am2[3] *= inv2;          \
      ci2[0] *= inv2; ci2[1] *= inv2; ci2[2] *= inv2; ci2[3] *= inv2;          \
      GR *= inv2;                                                              \
    }                                                                          \
  }

// QUAD: 4 steps, phases .w(+reload), .x, .y, .z — first step of every chunk
// consumes stream index === 3 (mod 4), so QUADs stay aligned throughout.
#define QUAD(NORM4)                                                            \
    STEP(EmA2, EmB2, 0, sy.w, 1)                                               \
    STEP(EmB2, EmA2, 0, sy.x, 0)                                               \
    STEP(EmA2, EmB2, 0, sy.y, 0)                                               \
    STEP(EmB2, EmA2, NORM4, sy.z, 0)

    // 63 chunks x 16 steps (t = 1..1008); norm every 4th chunk (64 steps)
    for (int c = 0; c < 63; ++c) {
        int nf = ((c & 3) == 3);
        QUAD(0) QUAD(0) QUAD(0) QUAD(nf)
    }
    // tail: t = 1009..1023 (15 steps), norm at the final step
    QUAD(0) QUAD(0) QUAD(0)
    STEP(EmA2, EmB2, 0, sy.w, 1)
    STEP(EmB2, EmA2, 0, sy.x, 0)
    STEP(EmA2, EmB2, 1, sy.y, 0)
#undef QUAD
#undef STEP
#undef AM
#undef CI

    if (lane == 0) out[b] = ll2 * 0.69314718055994530942f;
}

extern "C" void kernel_launch(void* const* d_in, const int* in_sizes, int n_in,
                              void* d_out, int out_size, void* d_ws, size_t ws_size,
                              hipStream_t stream) {
    const int*   seq   = (const int*)d_in[0];
    const float* em    = (const float*)d_in[1];
    const float* ins   = (const float*)d_in[2];
    const float* flank = (const float*)d_in[3];
    const float* btm   = (const float*)d_in[4];
    const float* m2e   = (const float*)d_in[5];
    const float* mtm   = (const float*)d_in[6];
    const float* m2i   = (const float*)d_in[7];
    const float* i2m   = (const float*)d_in[8];
    const float* i2i   = (const float*)d_in[9];
    const float* mtd   = (const float*)d_in[10];
    const float* dtm   = (const float*)d_in[11];
    const float* dtd   = (const float*)d_in[12];
    const float* lfl   = (const float*)d_in[13];
    const float* lfe   = (const float*)d_in[14];
    const float* e2u   = (const float*)d_in[15];
    const float* e2r   = (const float*)d_in[16];
    const float* e2t   = (const float*)d_in[17];
    float* P = (float*)d_ws;  // needs 71680 B
    float* out = (float*)d_out;

    hipLaunchKernelGGL(hmm_prep, dim3(8), dim3(64), 0, stream,
        em, ins, flank, btm, m2e, mtm, m2i, i2m, i2i, mtd, dtm, dtd,
        lfl, lfe, e2u, e2r, e2t, P);
    hipLaunchKernelGGL(hmm_forward, dim3(128), dim3(64), 0, stream, seq, P, out);
}